// Round 1
// baseline (101.586 us; speedup 1.0000x reference)
//
#include <hip/hip_runtime.h>
#include <cmath>

#define NB 4
#define SEQ 1024
#define SM1 1023
#define VOC 32000
#define V4 (VOC / 4)

struct MST { float m, s, t; };

// merge two online-softmax accumulators: m=max, s=sum exp(l-m), t=sum exp(l-m)*(l-m)
__device__ __forceinline__ MST mst_merge(MST a, MST b) {
    float M = fmaxf(a.m, b.m);
    float ca = __expf(a.m - M);
    float cb = __expf(b.m - M);
    MST r;
    r.m = M;
    r.s = fmaf(a.s, ca, b.s * cb);
    r.t = ca * fmaf(a.m - M, a.s, a.t) + cb * fmaf(b.m - M, b.s, b.t);
    return r;
}

// One block per (b, s) row: streams V=32000 logits once, online (m,S,T).
__global__ __launch_bounds__(256) void k_rows(const float* __restrict__ logits,
                                              const int* __restrict__ input_ids,
                                              float* __restrict__ out,
                                              float* __restrict__ ent_ws) {
    const int s = blockIdx.x;           // 0..1022
    const int b = blockIdx.y;           // 0..3
    const int tid = threadIdx.x;
    const size_t rowoff = (size_t)(b * SEQ + s) * VOC;
    const float4* __restrict__ row4 = (const float4*)(logits + rowoff);

    float m = -1e30f, S = 0.f, T = 0.f;
    for (int j = tid; j < V4; j += 256) {
        float4 x4 = row4[j];
        float xs[4] = {x4.x, x4.y, x4.z, x4.w};
        #pragma unroll
        for (int c = 0; c < 4; ++c) {
            float x = xs[c];
            if (x > m) {
                float cf = __expf(m - x);
                T = cf * fmaf(m - x, S, T);   // rescale old T, new elem adds 0
                S = fmaf(S, cf, 1.0f);        // rescale old S, new elem adds 1
                m = x;
            } else {
                float e = __expf(x - m);
                S += e;
                T = fmaf(e, x - m, T);
            }
        }
    }

    MST v{m, S, T};
    #pragma unroll
    for (int off = 32; off > 0; off >>= 1) {
        MST o;
        o.m = __shfl_xor(v.m, off);
        o.s = __shfl_xor(v.s, off);
        o.t = __shfl_xor(v.t, off);
        v = mst_merge(v, o);
    }

    __shared__ MST smst[4];
    const int lane = tid & 63, wid = tid >> 6;
    if (lane == 0) smst[wid] = v;
    __syncthreads();
    if (tid == 0) {
        MST r = smst[0];
        r = mst_merge(r, smst[1]);
        r = mst_merge(r, smst[2]);
        r = mst_merge(r, smst[3]);
        float logS = logf(r.s);
        int chosen = input_ids[b * SEQ + s + 1];
        float lc = logits[rowoff + (size_t)chosen];
        int row = b * SM1 + s;
        out[1 + row] = lc - r.m - logS;          // per_token_logps (TEMP=1)
        ent_ws[row] = logS - r.t / r.s;          // token_entropy
    }
}

// One block per b: mask sums, cumsum-gated truncated entropy, per-sample averages.
__global__ __launch_bounds__(1024) void k_persample(const int* __restrict__ labels,
                                                    const float* __restrict__ ent_ws,
                                                    float* __restrict__ out,
                                                    float* __restrict__ masksum_ws) {
    const int b = blockIdx.x;
    const int tid = threadIdx.x;
    const int lane = tid & 63, wid = tid >> 6;
    const bool has = tid < SM1;
    const int lab = has ? labels[b * SEQ + tid + 1] : 0;
    const float ent = has ? ent_ws[b * SM1 + tid] : 0.f;
    const int valid = (lab == 1) ? 1 : 0;

    // block-wide inclusive scan of `valid`
    int x = valid;
    #pragma unroll
    for (int off = 1; off < 64; off <<= 1) {
        int y = __shfl_up(x, off);
        if (lane >= off) x += y;
    }
    __shared__ int wsum[16];
    if (lane == 63) wsum[wid] = x;
    __syncthreads();
    if (tid == 0) {
        int acc = 0;
        #pragma unroll
        for (int i = 0; i < 16; ++i) { int t = wsum[i]; wsum[i] = acc; acc += t; }
    }
    __syncthreads();
    const int cum = x + wsum[wid];
    const int ecm = (valid && cum >= 4 && cum <= 100) ? 1 : 0;

    const float maskf = (float)valid;
    float4 acc;
    acc.x = maskf;               // sum(mask)
    acc.y = ent * maskf;         // sum(entropy*mask)
    acc.z = (float)ecm;          // sum(entropy_calc_mask)
    acc.w = ent * (float)ecm;    // sum(entropy*entropy_calc_mask)

    #pragma unroll
    for (int off = 32; off > 0; off >>= 1) {
        acc.x += __shfl_xor(acc.x, off);
        acc.y += __shfl_xor(acc.y, off);
        acc.z += __shfl_xor(acc.z, off);
        acc.w += __shfl_xor(acc.w, off);
    }
    __shared__ float4 wacc[16];
    if (lane == 0) wacc[wid] = acc;
    __syncthreads();
    if (tid == 0) {
        float4 t = wacc[0];
        #pragma unroll
        for (int i = 1; i < 16; ++i) {
            t.x += wacc[i].x; t.y += wacc[i].y; t.z += wacc[i].z; t.w += wacc[i].w;
        }
        out[1 + NB * SM1 + b]      = t.y / t.x;   // avg_entropy_per_sample
        out[1 + NB * SM1 + NB + b] = t.w / t.z;   // avg_entropy_truncated
        masksum_ws[b] = t.x;
    }
}

// ratio == exp(0) == 1 -> per_token_loss = -adv[b]; loss = -(sum adv_b*masksum_b)/sum(masksum)
__global__ void k_loss(const float* __restrict__ adv,
                       const float* __restrict__ masksum_ws,
                       float* __restrict__ out) {
    if (threadIdx.x == 0 && blockIdx.x == 0) {
        float tot = 0.f, num = 0.f;
        #pragma unroll
        for (int b = 0; b < NB; ++b) {
            float ms = masksum_ws[b];
            tot += ms;
            num = fmaf(adv[b], ms, num);
        }
        out[0] = -num / tot;
    }
}

extern "C" void kernel_launch(void* const* d_in, const int* in_sizes, int n_in,
                              void* d_out, int out_size, void* d_ws, size_t ws_size,
                              hipStream_t stream) {
    const float* logits    = (const float*)d_in[0];
    const int*   input_ids = (const int*)d_in[1];
    const int*   labels    = (const int*)d_in[2];
    const float* adv       = (const float*)d_in[3];
    float* out = (float*)d_out;
    float* ent_ws = (float*)d_ws;                 // NB*SM1 floats
    float* masksum_ws = ent_ws + NB * SM1;        // NB floats

    k_rows<<<dim3(SM1, NB), 256, 0, stream>>>(logits, input_ids, out, ent_ws);
    k_persample<<<NB, 1024, 0, stream>>>(labels, ent_ws, out, masksum_ws);
    k_loss<<<1, 64, 0, stream>>>(adv, masksum_ws, out);
}

// Round 2
// 95.299 us; speedup vs baseline: 1.0660x; 1.0660x over previous
//
#include <hip/hip_runtime.h>
#include <cmath>

#define NB 4
#define SEQ 1024
#define SM1 1023
#define VOC 32000
#define V4 (VOC / 4)

typedef float f4 __attribute__((ext_vector_type(4)));

struct MST { float m, s, t; };

// merge two online-softmax accumulators: m=max, s=sum exp(l-m), t=sum exp(l-m)*(l-m)
__device__ __forceinline__ MST mst_merge(MST a, MST b) {
    float M = fmaxf(a.m, b.m);
    float ca = __expf(a.m - M);
    float cb = __expf(b.m - M);
    MST r;
    r.m = M;
    r.s = fmaf(a.s, ca, b.s * cb);
    r.t = ca * fmaf(a.m - M, a.s, a.t) + cb * fmaf(b.m - M, b.s, b.t);
    return r;
}

__device__ __forceinline__ void upd(float x, float& m, float& S, float& T) {
    if (x > m) {
        float cf = __expf(m - x);
        T = cf * fmaf(m - x, S, T);   // rescale old T; new elem contributes 0
        S = fmaf(S, cf, 1.0f);        // rescale old S; new elem contributes 1
        m = x;
    } else {
        float e = __expf(x - m);
        S += e;
        T = fmaf(e, x - m, T);
    }
}

// One block per (b, s) row: streams V=32000 logits once with NT float4 loads,
// two independent online (m,S,T) accumulator chains per thread for MLP/ILP.
__global__ __launch_bounds__(256) void k_rows(const float* __restrict__ logits,
                                              const int* __restrict__ input_ids,
                                              float* __restrict__ out,
                                              float* __restrict__ ent_ws) {
    const int s = blockIdx.x;           // 0..1022
    const int b = blockIdx.y;           // 0..3
    const int tid = threadIdx.x;
    const size_t rowoff = (size_t)(b * SEQ + s) * VOC;
    const f4* __restrict__ row4 = (const f4*)(logits + rowoff);

    // issue the chosen-logit load early (independent of the stream)
    float lc = 0.f;
    if (tid == 0) {
        int chosen = input_ids[b * SEQ + s + 1];
        lc = logits[rowoff + (size_t)chosen];
    }

    float m0 = -1e30f, S0 = 0.f, T0 = 0.f;
    float m1 = -1e30f, S1 = 0.f, T1 = 0.f;

    int j = tid;
    // pairs (j, j+256), stepping 512: full, non-overlapping coverage with the tail below
    for (; j + 256 < V4; j += 512) {
        f4 xa = __builtin_nontemporal_load(row4 + j);
        f4 xb = __builtin_nontemporal_load(row4 + j + 256);
        upd(xa.x, m0, S0, T0); upd(xa.y, m0, S0, T0);
        upd(xa.z, m0, S0, T0); upd(xa.w, m0, S0, T0);
        upd(xb.x, m1, S1, T1); upd(xb.y, m1, S1, T1);
        upd(xb.z, m1, S1, T1); upd(xb.w, m1, S1, T1);
    }
    if (j < V4) {  // leftover first-slot elements in [7744, 7936)
        f4 xa = __builtin_nontemporal_load(row4 + j);
        upd(xa.x, m0, S0, T0); upd(xa.y, m0, S0, T0);
        upd(xa.z, m0, S0, T0); upd(xa.w, m0, S0, T0);
    }

    MST v = mst_merge(MST{m0, S0, T0}, MST{m1, S1, T1});
    #pragma unroll
    for (int off = 32; off > 0; off >>= 1) {
        MST o;
        o.m = __shfl_xor(v.m, off);
        o.s = __shfl_xor(v.s, off);
        o.t = __shfl_xor(v.t, off);
        v = mst_merge(v, o);
    }

    __shared__ MST smst[4];
    const int lane = tid & 63, wid = tid >> 6;
    if (lane == 0) smst[wid] = v;
    __syncthreads();
    if (tid == 0) {
        MST r = smst[0];
        r = mst_merge(r, smst[1]);
        r = mst_merge(r, smst[2]);
        r = mst_merge(r, smst[3]);
        float logS = logf(r.s);
        int row = b * SM1 + s;
        out[1 + row] = lc - r.m - logS;          // per_token_logps (TEMP=1)
        ent_ws[row] = logS - r.t / r.s;          // token_entropy
    }
}

// Single block: per-sample averages (with cumsum-gated truncated entropy) + scalar loss.
// ratio == exp(0) == 1 -> per_token_loss = -adv[b]; loss = -(sum adv_b*masksum_b)/sum(masksum)
__global__ __launch_bounds__(1024) void k_tail(const int* __restrict__ labels,
                                               const float* __restrict__ ent_ws,
                                               const float* __restrict__ adv,
                                               float* __restrict__ out) {
    const int tid = threadIdx.x;
    const int lane = tid & 63, wid = tid >> 6;
    __shared__ int wsum[16];
    __shared__ float4 wacc[16];
    __shared__ float msum[NB];

    for (int b = 0; b < NB; ++b) {
        const bool has = tid < SM1;
        const int lab = has ? labels[b * SEQ + tid + 1] : 0;
        const float ent = has ? ent_ws[b * SM1 + tid] : 0.f;
        const int valid = (lab == 1) ? 1 : 0;

        // block-wide inclusive scan of `valid`
        int x = valid;
        #pragma unroll
        for (int off = 1; off < 64; off <<= 1) {
            int y = __shfl_up(x, off);
            if (lane >= off) x += y;
        }
        if (lane == 63) wsum[wid] = x;
        __syncthreads();
        int woff = 0;
        #pragma unroll
        for (int i = 0; i < 16; ++i) woff += (i < wid) ? wsum[i] : 0;
        const int cum = woff + x;
        const int ecm = (valid && cum >= 4 && cum <= 100) ? 1 : 0;

        float4 acc;
        acc.x = (float)valid;
        acc.y = ent * (float)valid;
        acc.z = (float)ecm;
        acc.w = ent * (float)ecm;
        #pragma unroll
        for (int off = 32; off > 0; off >>= 1) {
            acc.x += __shfl_xor(acc.x, off);
            acc.y += __shfl_xor(acc.y, off);
            acc.z += __shfl_xor(acc.z, off);
            acc.w += __shfl_xor(acc.w, off);
        }
        if (lane == 0) wacc[wid] = acc;
        __syncthreads();
        if (tid == 0) {
            float4 t = wacc[0];
            #pragma unroll
            for (int i = 1; i < 16; ++i) {
                t.x += wacc[i].x; t.y += wacc[i].y;
                t.z += wacc[i].z; t.w += wacc[i].w;
            }
            out[1 + NB * SM1 + b]      = t.y / t.x;   // avg_entropy_per_sample
            out[1 + NB * SM1 + NB + b] = t.w / t.z;   // avg_entropy_truncated
            msum[b] = t.x;
        }
        __syncthreads();
    }

    if (tid == 0) {
        float tot = 0.f, num = 0.f;
        #pragma unroll
        for (int b = 0; b < NB; ++b) {
            tot += msum[b];
            num = fmaf(adv[b], msum[b], num);
        }
        out[0] = -num / tot;
    }
}

extern "C" void kernel_launch(void* const* d_in, const int* in_sizes, int n_in,
                              void* d_out, int out_size, void* d_ws, size_t ws_size,
                              hipStream_t stream) {
    const float* logits    = (const float*)d_in[0];
    const int*   input_ids = (const int*)d_in[1];
    const int*   labels    = (const int*)d_in[2];
    const float* adv       = (const float*)d_in[3];
    float* out = (float*)d_out;
    float* ent_ws = (float*)d_ws;                 // NB*SM1 floats

    k_rows<<<dim3(SM1, NB), 256, 0, stream>>>(logits, input_ids, out, ent_ws);
    k_tail<<<1, 1024, 0, stream>>>(labels, ent_ws, adv, out);
}